// Round 14
// baseline (44.175 us; speedup 1.0000x reference)
//
#include <hip/hip_runtime.h>
#include <math.h>

#define N_ 4096
#define L_ 32
#define K_ 8
#define Dc_ 64
#define Db_ 64
#define Dd_ 16
#define C_ 8
#define B_ 32
#define M_ 1000
#define LOG2PI_ 1.8378770664093453f

// output layout (floats): [0]=-elbo [1]=LL [2]=KL_z [3]=KL_s
// [4 .. 4+N*K) = rik ; then term_1 (M), term_2 (M), term_3 (M)
#define OUT_RIK 4
#define OUT_T1 (4 + N_ * K_)

// ws float-offsets
#define WS_PART 0                 // 32*64*48 = 98304 floats: per (b, rt) 3x16 (k-summed)
#define WS_LLP  98304             // 1024 floats: per-block LL partials (b*32+mt)
#define WS_WP   99328             // 65536 ushorts (32768 floats): bf16 weight frags
#define WS_BIAS (WS_WP + 32768)   // 2048 floats (raw bias per (k,f))
#define WS_IV   (WS_BIAS + 2048)  // 512 floats
#define WS_C1   (WS_IV + 512)     // 9 floats: per-k const1 + [8]=total

typedef __attribute__((ext_vector_type(8))) short short8v;
typedef __attribute__((ext_vector_type(4))) float f32x4;

__device__ inline unsigned short f2bf(float f) {
    unsigned u = __builtin_bit_cast(unsigned, f);
    unsigned r = u + 0x7FFFu + ((u >> 16) & 1u);   // round-to-nearest-even
    return (unsigned short)(r >> 16);
}

// ---------------- prep: W-frags, bias/iv/c1, rik ----------------
#define PW  65536
#define PB  (PW + 2048)
#define PIV (PB + 512)
#define PC1 (PIV + 9)
#define PRK (PC1 + N_ * K_)

__global__ __launch_bounds__(256) void mm_prep(
    const int* __restrict__ pidx, const float* __restrict__ qs_all,
    const float* __restrict__ Wg, const float* __restrict__ bg, const float* __restrict__ lvg,
    const float* __restrict__ Wb, const float* __restrict__ bb,
    const float* __restrict__ Wd, const float* __restrict__ bd,
    float* __restrict__ out, float* __restrict__ ws)
{
    const int t = blockIdx.x * 256 + threadIdx.x;
    unsigned short* wpw = (unsigned short*)(ws + WS_WP);

    if (t < PW) {
        // weight fragment elem: [k][ft][lane][j] ; feature = ft*16+(lane&15); l = (lane>>4)*8+j
        int j = t & 7, lane = (t >> 3) & 63, ft = (t >> 9) & 15, k = t >> 13;
        int f = ft * 16 + (lane & 15);
        int l = (lane >> 4) * 8 + j;
        float w;
        if (f < 64)       w = Wg[((size_t)k * 64 + f) * L_ + l];
        else if (f < 128) w = Wb[((size_t)k * 64 + (f - 64)) * L_ + l];
        else { int d = (f - 128) >> 3, c = f & 7; w = Wd[(((size_t)k * 16 + d) * 8 + c) * L_ + l]; }
        wpw[t] = f2bf(w);
    } else if (t < PB) {
        int i = t - PW; int k = i >> 8, f = i & 255;
        float v;
        if (f < 64)       v = bg[k * 64 + f];
        else if (f < 128) v = bb[k * 64 + f - 64];
        else { int d = (f - 128) >> 3, c = f & 7; v = bd[(k * 16 + d) * 8 + c]; }
        ws[WS_BIAS + i] = v;
    } else if (t < PIV) {
        int i = t - PB;
        ws[WS_IV + i] = __expf(-lvg[i]);
    } else if (t < PC1) {
        int k = t - PIV;
        if (k < 8) {
            float s = 0.f;
            for (int d = 0; d < 64; ++d) s += LOG2PI_ + lvg[k * 64 + d];
            ws[WS_C1 + k] = s;
        } else {
            float s = 0.f;
            for (int i = 0; i < 512; ++i) s += LOG2PI_ + lvg[i];
            ws[WS_C1 + 8] = s;
        }
    } else if (t < PRK) {
        int i = t - PC1;               // [0, N*K)
        int r = i >> 3, c = i & 7;
        int start = B_ * pidx[0];
        float v = 0.f;
        if (r >= start && r < start + B_) {
            const float* row = qs_all + (size_t)r * K_;
            float mx = row[0];
            #pragma unroll
            for (int jj = 1; jj < K_; ++jj) mx = fmaxf(mx, row[jj]);
            float se = 0.f;
            #pragma unroll
            for (int jj = 0; jj < K_; ++jj) se += __expf(row[jj] - mx);
            v = __expf(row[c] - mx) / se;
        }
        out[OUT_RIK + i] = v;
    }
}

// ---------------- main: grid (32 mt, 32 b); 512 thr = 8 waves ----------------
// Two 16-row m-tiles per block; wave owns 2 feature-tiles. VGPR target <= 64
// (launch_bounds 512,4 -> 4 blocks/CU = 8 waves/SIMD for latency hiding).
//   waves 0-3: (Gauss ft=w, Bern ft=4+w)
//   waves 4-7: (Cat ft=8+2u, Cat ft=9+2u)   (u = w-4)
__global__ __launch_bounds__(512, 4) void mm_main(
    const int* __restrict__ pidx,
    const float* __restrict__ Xc, const float* __restrict__ Xb, const int* __restrict__ Xd,
    const float* __restrict__ qm_all, const float* __restrict__ qlv_all,
    const float* __restrict__ qs_all, const float* __restrict__ eps,
    float* __restrict__ ws)
{
    const int tid = threadIdx.x, w = tid >> 6, lane = tid & 63;
    const int mt = blockIdx.x, b = blockIdx.y;
    const int l15 = lane & 15, lg = lane >> 4;
    const int fr = 4 * lg;
    const int start = B_ * pidx[0];
    const unsigned short* wp = (const unsigned short*)(ws + WS_WP);

    __shared__ __align__(16) unsigned int zu[512];     // 2 tiles * 512 bf16
    __shared__ __align__(16) float scin[2048];         // bias (-Xc for f<64) per (k,f)
    __shared__ __align__(16) float siv[512];
    __shared__ float sqk[8];
    __shared__ float sred[8][2][2][16];
    __shared__ float llred[8];

    // ---- stage z fragments (256 thr: 32 rows x 8 l-quads) ----
    if (tid < 256) {
        int m_loc = tid >> 3, l0 = (tid & 7) * 4;
        int m_glob = mt * 32 + m_loc;
        float4 e = make_float4(0.f, 0.f, 0.f, 0.f);
        if (m_glob < M_) e = *(const float4*)(eps + ((size_t)b * M_ + m_glob) * L_ + l0);
        float4 qm4 = *(const float4*)(qm_all + (size_t)(start + b) * L_ + l0);
        float4 ql4 = *(const float4*)(qlv_all + (size_t)(start + b) * L_ + l0);
        float z0 = qm4.x + __expf(0.5f * ql4.x) * e.x;
        float z1 = qm4.y + __expf(0.5f * ql4.y) * e.y;
        float z2 = qm4.z + __expf(0.5f * ql4.z) * e.z;
        float z3 = qm4.w + __expf(0.5f * ql4.w) * e.w;
        unsigned u0 = (unsigned)f2bf(z0) | ((unsigned)f2bf(z1) << 16);
        unsigned u1 = (unsigned)f2bf(z2) | ((unsigned)f2bf(z3) << 16);
        int widx = (m_loc >> 4) * 256 + ((l0 >> 3) * 16 + (m_loc & 15)) * 4 + ((l0 & 7) >> 1);
        zu[widx] = u0; zu[widx + 1] = u1;
    }
    {   // cinit: k = tid>>6, f = (tid&63)*4 ; bias from ws, -Xc folded for f<64
        int f = (tid & 63) * 4;
        float4 bv = *(const float4*)(ws + WS_BIAS + tid * 4);
        if (f < 64) {
            float4 xc = *(const float4*)(Xc + b * 64 + f);
            bv.x -= xc.x; bv.y -= xc.y; bv.z -= xc.z; bv.w -= xc.w;
        }
        ((float4*)scin)[tid] = bv;
    }
    if (tid < 128) ((float4*)siv)[tid] = *(const float4*)(ws + WS_IV + tid * 4);
    if (tid < 8)   sqk[tid] = qs_all[(size_t)(start + b) * K_ + tid];
    __syncthreads();

    const unsigned short* zp = (const unsigned short*)zu;
    const short8v zbA = *(const short8v*)(zp + lane * 8);
    const short8v zbB = *(const short8v*)(zp + 512 + lane * 8);

    // ---- wave->feature-tile mapping (balanced) ----
    const int u = w & 3;                               // w-4 for cat waves
    const int ftA = (w < 4) ? w : (8 + 2 * u);
    const int ftB = (w < 4) ? (4 + w) : (9 + 2 * u);

    // ---- hoisted constants ----
    const float4 xf = *(const float4*)(Xb + b * 64 + u * 16 + fr);   // Bern x (waves 0-3)
    const int dA = 4 * u + (lg >> 1);                  // cat tile A d-index (w>=4)
    const int dB = 4 * u + 2 + (lg >> 1);              // cat tile B d-index
    const int xdA = Xd[b * 16 + dA];
    const int xdB = Xd[b * 16 + dB];
    const int cc0 = 4 * (lg & 1);
    float4 is3A, is3B;
    is3A.x = (cc0 + 0 == xdA) ? 1.f : 0.f;  is3A.y = (cc0 + 1 == xdA) ? 1.f : 0.f;
    is3A.z = (cc0 + 2 == xdA) ? 1.f : 0.f;  is3A.w = (cc0 + 3 == xdA) ? 1.f : 0.f;
    is3B.x = (cc0 + 0 == xdB) ? 1.f : 0.f;  is3B.y = (cc0 + 1 == xdB) ? 1.f : 0.f;
    is3B.z = (cc0 + 2 == xdB) ? 1.f : 0.f;  is3B.w = (cc0 + 3 == xdB) ? 1.f : 0.f;

    float taA = 0.f, taB = 0.f;     // tile-A term, per m-tile
    float tbA = 0.f, tbB = 0.f;     // tile-B term, per m-tile
    float llA = 0.f, llB = 0.f;

#define GAUSS_EPI(dd, ta_, ll_) { \
    float s_ = 0.f; \
    s_ = fmaf(dd[0] * dd[0], iv4.x, s_); \
    s_ = fmaf(dd[1] * dd[1], iv4.y, s_); \
    s_ = fmaf(dd[2] * dd[2], iv4.z, s_); \
    s_ = fmaf(dd[3] * dd[3], iv4.w, s_); \
    ta_ += s_; ll_ = fmaf(qm5, s_, ll_); }

#define BERN_EPI(dd, tb_, ll_) { \
    float s_ = 0.f, lgt_, sp_; \
    lgt_ = dd[0]; sp_ = fmaxf(lgt_, 0.f) + __logf(1.f + __expf(-fabsf(lgt_))); s_ += xf.x * lgt_ - sp_; \
    lgt_ = dd[1]; sp_ = fmaxf(lgt_, 0.f) + __logf(1.f + __expf(-fabsf(lgt_))); s_ += xf.y * lgt_ - sp_; \
    lgt_ = dd[2]; sp_ = fmaxf(lgt_, 0.f) + __logf(1.f + __expf(-fabsf(lgt_))); s_ += xf.z * lgt_ - sp_; \
    lgt_ = dd[3]; sp_ = fmaxf(lgt_, 0.f) + __logf(1.f + __expf(-fabsf(lgt_))); s_ += xf.w * lgt_ - sp_; \
    tb_ += s_; ll_ = fmaf(qkv, s_, ll_); }

#define CAT_EPI(dd, is_, tb_, ll_) { \
    float e4_ = __expf(dd[0]) + __expf(dd[1]) + __expf(dd[2]) + __expf(dd[3]); \
    float se_ = e4_ + __shfl_xor(e4_, 16, 64); \
    float u_  = is_.x * dd[0] + is_.y * dd[1] + is_.z * dd[2] + is_.w * dd[3]; \
    float tm_ = u_ - 0.5f * __logf(se_); \
    tb_ += tm_; ll_ = fmaf(qkv, tm_, ll_); }

    #pragma unroll 2
    for (int k = 0; k < K_; ++k) {
        const short8v wfA = *(const short8v*)(wp + ((size_t)(k * 16 + ftA)) * 512 + lane * 8);
        const short8v wfB = *(const short8v*)(wp + ((size_t)(k * 16 + ftB)) * 512 + lane * 8);
        const float4 cA = *(const float4*)(scin + k * 256 + ftA * 16 + fr);
        const float4 cB = *(const float4*)(scin + k * 256 + ftB * 16 + fr);
        const float qkv = sqk[k];

        const f32x4 ciA = {cA.x, cA.y, cA.z, cA.w};
        const f32x4 ciB = {cB.x, cB.y, cB.z, cB.w};
        f32x4 dA0 = __builtin_amdgcn_mfma_f32_16x16x32_bf16(wfA, zbA, ciA, 0, 0, 0);
        f32x4 dA1 = __builtin_amdgcn_mfma_f32_16x16x32_bf16(wfA, zbB, ciA, 0, 0, 0);
        f32x4 dB0 = __builtin_amdgcn_mfma_f32_16x16x32_bf16(wfB, zbA, ciB, 0, 0, 0);
        f32x4 dB1 = __builtin_amdgcn_mfma_f32_16x16x32_bf16(wfB, zbB, ciB, 0, 0, 0);

        if (w < 4) {             // Gauss on tile A, Bern on tile B
            const float4 iv4 = *(const float4*)(siv + k * 64 + w * 16 + fr);
            const float qm5 = -0.5f * qkv;
            GAUSS_EPI(dA0, taA, llA)
            GAUSS_EPI(dA1, taB, llB)
            BERN_EPI(dB0, tbA, llA)
            BERN_EPI(dB1, tbB, llB)
        } else {                 // two categorical tiles
            CAT_EPI(dA0, is3A, taA, llA)
            CAT_EPI(dA1, is3A, taB, llB)
            CAT_EPI(dB0, is3B, tbA, llA)
            CAT_EPI(dB1, is3B, tbB, llB)
        }
    }

    // ---- deferred masking + reductions ----
    const int mrow = mt * 32 + l15;
    if (mrow      >= M_) { taA = 0.f; tbA = 0.f; llA = 0.f; }
    if (mrow + 16 >= M_) { taB = 0.f; tbB = 0.f; llB = 0.f; }

    float tarA = taA + __shfl_xor(taA, 16, 64); tarA += __shfl_xor(tarA, 32, 64);
    float tarB = taB + __shfl_xor(taB, 16, 64); tarB += __shfl_xor(tarB, 32, 64);
    float tbrA = tbA + __shfl_xor(tbA, 16, 64); tbrA += __shfl_xor(tbrA, 32, 64);
    float tbrB = tbB + __shfl_xor(tbB, 16, 64); tbrB += __shfl_xor(tbrB, 32, 64);
    float llv = llA + llB;
    #pragma unroll
    for (int ofs = 1; ofs < 64; ofs <<= 1) llv += __shfl_xor(llv, ofs, 64);

    if (lane < 16) {
        sred[w][0][0][l15] = tarA; sred[w][1][0][l15] = tarB;
        sred[w][0][1][l15] = tbrA; sred[w][1][1][l15] = tbrB;
    }
    if (lane == 0) llred[w] = llv;
    __syncthreads();

    if (tid < 96) {
        int i = tid >> 5, tile = (tid >> 4) & 1, cx = tid & 15;
        int rt = mt * 2 + tile;
        float s;
        if (i == 0) {            // Gaussian quad sums (waves 0-3, slot 0)
            s = sred[0][tile][0][cx] + sred[1][tile][0][cx]
              + sred[2][tile][0][cx] + sred[3][tile][0][cx];
        } else if (i == 1) {     // Bernoulli (waves 0-3, slot 1)
            s = sred[0][tile][1][cx] + sred[1][tile][1][cx]
              + sred[2][tile][1][cx] + sred[3][tile][1][cx];
        } else {                 // Categorical (waves 4-7, both slots)
            s = 0.f;
            #pragma unroll
            for (int ww = 4; ww < 8; ++ww)
                s += sred[ww][tile][0][cx] + sred[ww][tile][1][cx];
        }
        ws[WS_PART + ((size_t)b * 64 + rt) * 48 + i * 16 + cx] = s;
    }
    if (tid == 96) {
        float s = 0.f;
        #pragma unroll
        for (int ww = 0; ww < 8; ++ww) s += llred[ww];
        float cterm = 0.f;
        #pragma unroll
        for (int k = 0; k < 8; ++k) cterm = fmaf(sqk[k], ws[WS_C1 + k], cterm);
        int nv = M_ - mt * 32; nv = (nv > 32) ? 32 : (nv < 0 ? 0 : nv);
        ws[WS_LLP + b * 32 + mt] = s - 0.5f * cterm * (float)nv;
    }
}

// ---------------- final: block 0 = LL/KL/elbo ; 1..12 = term_i[m] ----------------
__global__ __launch_bounds__(256) void mm_final(
    const int* __restrict__ pidx,
    const float* __restrict__ qm_all, const float* __restrict__ qlv_all,
    const float* __restrict__ qs_all,
    const float* __restrict__ pm_all, const float* __restrict__ pv_all,
    const float* __restrict__ pmu_all,
    const float* __restrict__ ws, float* __restrict__ out)
{
    const int tid = threadIdx.x;
    if (blockIdx.x == 0) {
        __shared__ float wred[4];
        __shared__ float skl[B_], sks[B_];
        const int start = B_ * pidx[0];
        float v = ws[WS_LLP + tid]       + ws[WS_LLP + 256 + tid]
                + ws[WS_LLP + 512 + tid] + ws[WS_LLP + 768 + tid];
        #pragma unroll
        for (int ofs = 1; ofs < 64; ofs <<= 1) v += __shfl_xor(v, ofs, 64);
        if ((tid & 63) == 0) wred[tid >> 6] = v;

        if (tid < B_) {
            int r = start + tid;
            float kl = 0.f;
            for (int l = 0; l < L_; ++l) {
                float qmv = qm_all[(size_t)r * L_ + l];
                float qlv = qlv_all[(size_t)r * L_ + l];
                float mp  = pm_all[(size_t)r * L_ + l];
                float vp  = pv_all[(size_t)r * L_ + l];
                float d   = qmv - mp;
                kl += __logf(vp) - qlv + (__expf(qlv) + d * d) / vp - 1.f;
            }
            skl[tid] = 0.5f * kl;

            float qsum = 0.f, psum = 0.f;
            #pragma unroll
            for (int j = 0; j < K_; ++j) {
                qsum += qs_all[(size_t)r * K_ + j];
                psum += pmu_all[(size_t)r * K_ + j];
            }
            float ks = 0.f;
            #pragma unroll
            for (int j = 0; j < K_; ++j) {
                float qn = qs_all[(size_t)r * K_ + j] / qsum;
                float pn = pmu_all[(size_t)r * K_ + j] / psum;
                ks += qn * (__logf(qn) - __logf(pn));
            }
            sks[tid] = ks;
        }
        __syncthreads();
        if (tid == 0) {
            float LL = wred[0] + wred[1] + wred[2] + wred[3];
            float sklz = 0.f, skls = 0.f;
            for (int i = 0; i < B_; ++i) { sklz += skl[i]; skls += sks[i]; }
            float elbo = LL - sklz - skls;
            out[0] = -elbo;
            out[1] = LL;
            out[2] = skl[B_ - 1];
            out[3] = sks[B_ - 1];
        }
    } else {
        int g = (blockIdx.x - 1) * 256 + tid;
        if (g < 3 * M_) {
            int i = g / M_, m = g % M_;
            int rt = m >> 4, cx = m & 15;
            float s = 0.f;
            #pragma unroll 8
            for (int b2 = 0; b2 < 32; ++b2)
                s += ws[WS_PART + ((size_t)b2 * 64 + rt) * 48 + i * 16 + cx];
            if (i == 0) s = -0.5f * (32.f * ws[WS_C1 + 8] + s);
            out[OUT_T1 + i * M_ + m] = s;
        }
    }
}

extern "C" void kernel_launch(void* const* d_in, const int* in_sizes, int n_in,
                              void* d_out, int out_size, void* d_ws, size_t ws_size,
                              hipStream_t stream)
{
    (void)in_sizes; (void)n_in; (void)out_size; (void)ws_size;
    const int*   pidx = (const int*)d_in[0];
    const float* Xc   = (const float*)d_in[1];
    const float* Xb   = (const float*)d_in[2];
    const int*   Xd   = (const int*)d_in[3];
    const float* qm   = (const float*)d_in[4];
    const float* qlv  = (const float*)d_in[5];
    const float* qs   = (const float*)d_in[6];
    const float* pm   = (const float*)d_in[7];
    const float* pv   = (const float*)d_in[8];
    const float* pmu  = (const float*)d_in[9];
    const float* Wg   = (const float*)d_in[10];
    const float* bg   = (const float*)d_in[11];
    const float* lvg  = (const float*)d_in[12];
    const float* Wb   = (const float*)d_in[13];
    const float* bb   = (const float*)d_in[14];
    const float* Wd   = (const float*)d_in[15];
    const float* bd   = (const float*)d_in[16];
    const float* eps  = (const float*)d_in[17];
    float* out = (float*)d_out;
    float* ws  = (float*)d_ws;

    mm_prep<<<(PRK + 255) / 256, 256, 0, stream>>>(pidx, qs, Wg, bg, lvg,
                                                   Wb, bb, Wd, bd, out, ws);

    dim3 grid(32, 32);   // (32-row m-group, b)
    mm_main<<<grid, 512, 0, stream>>>(pidx, Xc, Xb, Xd, qm, qlv, qs, eps, ws);

    mm_final<<<13, 256, 0, stream>>>(pidx, qm, qlv, qs, pm, pv, pmu, ws, out);
}

// Round 16
// 33.798 us; speedup vs baseline: 1.3070x; 1.3070x over previous
//
#include <hip/hip_runtime.h>
#include <math.h>

#define N_ 4096
#define L_ 32
#define K_ 8
#define Dc_ 64
#define Db_ 64
#define Dd_ 16
#define C_ 8
#define B_ 32
#define M_ 1000
#define LOG2PI_ 1.8378770664093453f
#define LOG2E_ 1.4426950408889634f
#define LN2_   0.6931471805599453f

// output layout (floats): [0]=-elbo [1]=LL [2]=KL_z [3]=KL_s
// [4 .. 4+N*K) = rik ; then term_1 (M), term_2 (M), term_3 (M)
#define OUT_RIK 4
#define OUT_T1 (4 + N_ * K_)

// ws float-offsets
#define WS_PART 0                 // 32*64*48 = 98304 floats: per (b, rt) 3x16 (k-summed)
#define WS_LLP  98304             // 512 floats: per-block LL partials (b*16+mt)
#define WS_WP   99328             // 65536 ushorts (32768 floats): bf16 weight frags
#define WS_BIAS (WS_WP + 32768)   // 2048 floats (bias per (k,f); f>=64 pre-scaled by log2e)
#define WS_IV   (WS_BIAS + 2048)  // 512 floats
#define WS_C1   (WS_IV + 512)     // 9 floats: per-k const1 + [8]=total

typedef __attribute__((ext_vector_type(8))) short short8v;
typedef __attribute__((ext_vector_type(4))) float f32x4;

#define EXP2F(x) __builtin_amdgcn_exp2f(x)   // v_exp_f32 (base-2)
#define LOG2F(x) __builtin_amdgcn_logf(x)    // v_log_f32 (base-2)

__device__ inline unsigned short f2bf(float f) {
    unsigned u = __builtin_bit_cast(unsigned, f);
    unsigned r = u + 0x7FFFu + ((u >> 16) & 1u);   // round-to-nearest-even
    return (unsigned short)(r >> 16);
}

// ---------------- prep: W-frags (Bern/Cat pre-scaled by log2e), bias/iv/c1 ----------------
#define PW  65536
#define PB  (PW + 2048)
#define PIV (PB + 512)
#define PC1 (PIV + 9)

__global__ __launch_bounds__(256) void mm_prep(
    const float* __restrict__ Wg, const float* __restrict__ bg, const float* __restrict__ lvg,
    const float* __restrict__ Wb, const float* __restrict__ bb,
    const float* __restrict__ Wd, const float* __restrict__ bd,
    float* __restrict__ ws)
{
    const int t = blockIdx.x * 256 + threadIdx.x;
    unsigned short* wpw = (unsigned short*)(ws + WS_WP);

    if (t < PW) {
        // weight fragment elem: [k][ft][lane][j] ; feature = ft*16+(lane&15); l = (lane>>4)*8+j
        int j = t & 7, lane = (t >> 3) & 63, ft = (t >> 9) & 15, k = t >> 13;
        int f = ft * 16 + (lane & 15);
        int l = (lane >> 4) * 8 + j;
        float w;
        if (f < 64)       w = Wg[((size_t)k * 64 + f) * L_ + l];
        else if (f < 128) w = Wb[((size_t)k * 64 + (f - 64)) * L_ + l] * LOG2E_;
        else { int d = (f - 128) >> 3, c = f & 7; w = Wd[(((size_t)k * 16 + d) * 8 + c) * L_ + l] * LOG2E_; }
        wpw[t] = f2bf(w);
    } else if (t < PB) {
        int i = t - PW; int k = i >> 8, f = i & 255;
        float v;
        if (f < 64)       v = bg[k * 64 + f];
        else if (f < 128) v = bb[k * 64 + f - 64] * LOG2E_;
        else { int d = (f - 128) >> 3, c = f & 7; v = bd[(k * 16 + d) * 8 + c] * LOG2E_; }
        ws[WS_BIAS + i] = v;
    } else if (t < PIV) {
        int i = t - PB;
        ws[WS_IV + i] = __expf(-lvg[i]);
    } else if (t < PC1) {
        int k = t - PIV;
        if (k < 8) {
            float s = 0.f;
            for (int d = 0; d < 64; ++d) s += LOG2PI_ + lvg[k * 64 + d];
            ws[WS_C1 + k] = s;
        } else {
            float s = 0.f;
            for (int i = 0; i < 512; ++i) s += LOG2PI_ + lvg[i];
            ws[WS_C1 + 8] = s;
        }
    }
}

// ---------------- main: grid (16 mt, 32 b); 512 thr = 8 waves ----------------
// Four 16-row m-tiles per block. Wave w owns feature-tiles {w, 8+w}:
//   waves 0-3: Gauss (natural) + Cat (base-2) ; waves 4-7: Bern (base-2) + Cat (base-2)
// Bern/Cat logits arrive in base-2 (weights pre-scaled); epilogues use bare
// v_exp/v_log; ln2 scaling applied once after the k-loop.
__global__ __launch_bounds__(512, 2) void mm_main(
    const int* __restrict__ pidx,
    const float* __restrict__ Xc, const float* __restrict__ Xb, const int* __restrict__ Xd,
    const float* __restrict__ qm_all, const float* __restrict__ qlv_all,
    const float* __restrict__ qs_all, const float* __restrict__ eps,
    float* __restrict__ ws)
{
    const int tid = threadIdx.x, w = tid >> 6, lane = tid & 63;
    const int mt = blockIdx.x, b = blockIdx.y;
    const int l15 = lane & 15, lg = lane >> 4;
    const int fr = 4 * lg;
    const int start = B_ * pidx[0];
    const unsigned short* wp = (const unsigned short*)(ws + WS_WP);

    __shared__ __align__(16) unsigned int zu[1024];    // 4 tiles * 512 bf16
    __shared__ __align__(16) float scin[2048];         // bias (-Xc for f<64) per (k,f)
    __shared__ __align__(16) float siv[512];
    __shared__ float sqk[8];
    __shared__ float sred[8][4][2][16];
    __shared__ float llred[8];

    // ---- stage z fragments (512 thr: 64 rows x 8 l-quads) ----
    {
        int m_loc = tid >> 3, l0 = (tid & 7) * 4;
        int m_glob = mt * 64 + m_loc;
        float4 e = make_float4(0.f, 0.f, 0.f, 0.f);
        if (m_glob < M_) e = *(const float4*)(eps + ((size_t)b * M_ + m_glob) * L_ + l0);
        float4 qm4 = *(const float4*)(qm_all + (size_t)(start + b) * L_ + l0);
        float4 ql4 = *(const float4*)(qlv_all + (size_t)(start + b) * L_ + l0);
        float z0 = qm4.x + __expf(0.5f * ql4.x) * e.x;
        float z1 = qm4.y + __expf(0.5f * ql4.y) * e.y;
        float z2 = qm4.z + __expf(0.5f * ql4.z) * e.z;
        float z3 = qm4.w + __expf(0.5f * ql4.w) * e.w;
        unsigned u0 = (unsigned)f2bf(z0) | ((unsigned)f2bf(z1) << 16);
        unsigned u1 = (unsigned)f2bf(z2) | ((unsigned)f2bf(z3) << 16);
        int widx = (m_loc >> 4) * 256 + ((l0 >> 3) * 16 + (m_loc & 15)) * 4 + ((l0 & 7) >> 1);
        zu[widx] = u0; zu[widx + 1] = u1;
    }
    {   // cinit: k = tid>>6, f = (tid&63)*4 ; bias from ws, -Xc folded for f<64
        int f = (tid & 63) * 4;
        float4 bv = *(const float4*)(ws + WS_BIAS + tid * 4);
        if (f < 64) {
            float4 xc = *(const float4*)(Xc + b * 64 + f);
            bv.x -= xc.x; bv.y -= xc.y; bv.z -= xc.z; bv.w -= xc.w;
        }
        ((float4*)scin)[tid] = bv;
    }
    if (tid < 128) ((float4*)siv)[tid] = *(const float4*)(ws + WS_IV + tid * 4);
    if (tid < 8)   sqk[tid] = qs_all[(size_t)(start + b) * K_ + tid];
    __syncthreads();

    const unsigned short* zp = (const unsigned short*)zu;
    const short8v zbA = *(const short8v*)(zp + lane * 8);
    const short8v zbB = *(const short8v*)(zp + 512 + lane * 8);
    const short8v zbC = *(const short8v*)(zp + 1024 + lane * 8);
    const short8v zbD = *(const short8v*)(zp + 1536 + lane * 8);

    // ---- hoisted constants ----
    const float4 xf = *(const float4*)(Xb + b * 64 + (w & 3) * 16 + fr);  // used when w>=4
    const int d3 = 2 * w + (lg >> 1);
    const int xd = Xd[b * 16 + d3];
    const int cc0 = 4 * (lg & 1);
    float4 is3;
    is3.x = (cc0 + 0 == xd) ? 1.f : 0.f;  is3.y = (cc0 + 1 == xd) ? 1.f : 0.f;
    is3.z = (cc0 + 2 == xd) ? 1.f : 0.f;  is3.w = (cc0 + 3 == xd) ? 1.f : 0.f;

    float taA = 0.f, taB = 0.f, taC = 0.f, taD = 0.f;
    float tbA = 0.f, tbB = 0.f, tbC = 0.f, tbD = 0.f;
    float llA = 0.f, llB = 0.f, llC = 0.f, llD = 0.f;      // natural units (Gauss)
    float l2A = 0.f, l2B = 0.f, l2C = 0.f, l2D = 0.f;      // base-2 units (Bern+Cat)

#define GAUSS_EPI(dd, ta_, ll_) { \
    float s_ = 0.f; \
    s_ = fmaf(dd[0] * dd[0], iv4.x, s_); \
    s_ = fmaf(dd[1] * dd[1], iv4.y, s_); \
    s_ = fmaf(dd[2] * dd[2], iv4.z, s_); \
    s_ = fmaf(dd[3] * dd[3], iv4.w, s_); \
    ta_ += s_; ll_ = fmaf(qm5, s_, ll_); }

// base-2 softplus: contribution = xb*l2 - max(l2,0) - log2(1 + 2^(-|l2|))
#define BERN_EPI(dd, ta_, ll2_) { \
    float s_ = 0.f, lgt_; \
    lgt_ = dd[0]; s_ += xf.x * lgt_ - fmaxf(lgt_, 0.f) - LOG2F(1.f + EXP2F(-fabsf(lgt_))); \
    lgt_ = dd[1]; s_ += xf.y * lgt_ - fmaxf(lgt_, 0.f) - LOG2F(1.f + EXP2F(-fabsf(lgt_))); \
    lgt_ = dd[2]; s_ += xf.z * lgt_ - fmaxf(lgt_, 0.f) - LOG2F(1.f + EXP2F(-fabsf(lgt_))); \
    lgt_ = dd[3]; s_ += xf.w * lgt_ - fmaxf(lgt_, 0.f) - LOG2F(1.f + EXP2F(-fabsf(lgt_))); \
    ta_ += s_; ll2_ = fmaf(qkv, s_, ll2_); }

// base-2 log-sum-exp: tm = l2_sel - 0.5*log2(sum 2^l2)  (pair-duplicated)
#define CAT_EPI(dd, tb_, ll2_) { \
    float e4_ = EXP2F(dd[0]) + EXP2F(dd[1]) + EXP2F(dd[2]) + EXP2F(dd[3]); \
    float se_ = e4_ + __shfl_xor(e4_, 16, 64); \
    float u_  = is3.x * dd[0] + is3.y * dd[1] + is3.z * dd[2] + is3.w * dd[3]; \
    float tm_ = u_ - 0.5f * LOG2F(se_); \
    tb_ += tm_; ll2_ = fmaf(qkv, tm_, ll2_); }

    #pragma unroll 2
    for (int k = 0; k < K_; ++k) {
        const short8v wfA = *(const short8v*)(wp + ((size_t)(k * 16 + w))     * 512 + lane * 8);
        const short8v wfB = *(const short8v*)(wp + ((size_t)(k * 16 + 8 + w)) * 512 + lane * 8);
        const float4 cA = *(const float4*)(scin + k * 256 + w * 16 + fr);
        const float4 cB = *(const float4*)(scin + k * 256 + (8 + w) * 16 + fr);
        const float qkv = sqk[k];

        const f32x4 ciA = {cA.x, cA.y, cA.z, cA.w};
        const f32x4 ciB = {cB.x, cB.y, cB.z, cB.w};
        f32x4 dA0 = __builtin_amdgcn_mfma_f32_16x16x32_bf16(wfA, zbA, ciA, 0, 0, 0);
        f32x4 dA1 = __builtin_amdgcn_mfma_f32_16x16x32_bf16(wfA, zbB, ciA, 0, 0, 0);
        f32x4 dA2 = __builtin_amdgcn_mfma_f32_16x16x32_bf16(wfA, zbC, ciA, 0, 0, 0);
        f32x4 dA3 = __builtin_amdgcn_mfma_f32_16x16x32_bf16(wfA, zbD, ciA, 0, 0, 0);
        f32x4 dB0 = __builtin_amdgcn_mfma_f32_16x16x32_bf16(wfB, zbA, ciB, 0, 0, 0);
        f32x4 dB1 = __builtin_amdgcn_mfma_f32_16x16x32_bf16(wfB, zbB, ciB, 0, 0, 0);
        f32x4 dB2 = __builtin_amdgcn_mfma_f32_16x16x32_bf16(wfB, zbC, ciB, 0, 0, 0);
        f32x4 dB3 = __builtin_amdgcn_mfma_f32_16x16x32_bf16(wfB, zbD, ciB, 0, 0, 0);

        if (w < 4) {             // Gauss on tile A (natural units)
            const float4 iv4 = *(const float4*)(siv + k * 64 + w * 16 + fr);
            const float qm5 = -0.5f * qkv;
            GAUSS_EPI(dA0, taA, llA)
            GAUSS_EPI(dA1, taB, llB)
            GAUSS_EPI(dA2, taC, llC)
            GAUSS_EPI(dA3, taD, llD)
        } else {                 // Bern on tile A (base-2)
            BERN_EPI(dA0, taA, l2A)
            BERN_EPI(dA1, taB, l2B)
            BERN_EPI(dA2, taC, l2C)
            BERN_EPI(dA3, taD, l2D)
        }
        CAT_EPI(dB0, tbA, l2A)
        CAT_EPI(dB1, tbB, l2B)
        CAT_EPI(dB2, tbC, l2C)
        CAT_EPI(dB3, tbD, l2D)
    }

    // ---- scale base-2 accumulators to natural units ----
    if (w >= 4) { taA *= LN2_; taB *= LN2_; taC *= LN2_; taD *= LN2_; }
    tbA *= LN2_; tbB *= LN2_; tbC *= LN2_; tbD *= LN2_;
    llA = fmaf(LN2_, l2A, llA); llB = fmaf(LN2_, l2B, llB);
    llC = fmaf(LN2_, l2C, llC); llD = fmaf(LN2_, l2D, llD);

    // ---- deferred masking + reductions ----
    const int mrow = mt * 64 + l15;
    if (mrow      >= M_) { taA = 0.f; tbA = 0.f; llA = 0.f; }
    if (mrow + 16 >= M_) { taB = 0.f; tbB = 0.f; llB = 0.f; }
    if (mrow + 32 >= M_) { taC = 0.f; tbC = 0.f; llC = 0.f; }
    if (mrow + 48 >= M_) { taD = 0.f; tbD = 0.f; llD = 0.f; }

    float tarA = taA + __shfl_xor(taA, 16, 64); tarA += __shfl_xor(tarA, 32, 64);
    float tarB = taB + __shfl_xor(taB, 16, 64); tarB += __shfl_xor(tarB, 32, 64);
    float tarC = taC + __shfl_xor(taC, 16, 64); tarC += __shfl_xor(tarC, 32, 64);
    float tarD = taD + __shfl_xor(taD, 16, 64); tarD += __shfl_xor(tarD, 32, 64);
    float tbrA = tbA + __shfl_xor(tbA, 16, 64); tbrA += __shfl_xor(tbrA, 32, 64);
    float tbrB = tbB + __shfl_xor(tbB, 16, 64); tbrB += __shfl_xor(tbrB, 32, 64);
    float tbrC = tbC + __shfl_xor(tbC, 16, 64); tbrC += __shfl_xor(tbrC, 32, 64);
    float tbrD = tbD + __shfl_xor(tbD, 16, 64); tbrD += __shfl_xor(tbrD, 32, 64);
    float llv = llA + llB + llC + llD;
    #pragma unroll
    for (int ofs = 1; ofs < 64; ofs <<= 1) llv += __shfl_xor(llv, ofs, 64);

    if (lane < 16) {
        sred[w][0][0][l15] = tarA; sred[w][1][0][l15] = tarB;
        sred[w][2][0][l15] = tarC; sred[w][3][0][l15] = tarD;
        sred[w][0][1][l15] = tbrA; sred[w][1][1][l15] = tbrB;
        sred[w][2][1][l15] = tbrC; sred[w][3][1][l15] = tbrD;
    }
    if (lane == 0) llred[w] = llv;
    __syncthreads();

    if (tid < 192) {
        int i = tid >> 6, tile = (tid >> 4) & 3, cx = tid & 15;
        int rt = mt * 4 + tile;
        float s;
        if (i == 0) {            // Gaussian quad sums (waves 0-3, slot 0)
            s = sred[0][tile][0][cx] + sred[1][tile][0][cx]
              + sred[2][tile][0][cx] + sred[3][tile][0][cx];
        } else if (i == 1) {     // Bernoulli (waves 4-7, slot 0)
            s = sred[4][tile][0][cx] + sred[5][tile][0][cx]
              + sred[6][tile][0][cx] + sred[7][tile][0][cx];
        } else {                 // Categorical (all waves, slot 1)
            s = 0.f;
            #pragma unroll
            for (int ww = 0; ww < 8; ++ww) s += sred[ww][tile][1][cx];
        }
        ws[WS_PART + ((size_t)b * 64 + rt) * 48 + i * 16 + cx] = s;
    }
    if (tid == 192) {
        float s = 0.f;
        #pragma unroll
        for (int ww = 0; ww < 8; ++ww) s += llred[ww];
        float cterm = 0.f;
        #pragma unroll
        for (int k = 0; k < 8; ++k) cterm = fmaf(sqk[k], ws[WS_C1 + k], cterm);
        int nv = M_ - mt * 64; nv = (nv > 64) ? 64 : (nv < 0 ? 0 : nv);
        ws[WS_LLP + b * 16 + mt] = s - 0.5f * cterm * (float)nv;
    }
}

// ---------------- final: block 0 = LL/KL/elbo ; 1..12 = terms ; 13..140 = rik ----------------
__global__ __launch_bounds__(256) void mm_final(
    const int* __restrict__ pidx,
    const float* __restrict__ qm_all, const float* __restrict__ qlv_all,
    const float* __restrict__ qs_all,
    const float* __restrict__ pm_all, const float* __restrict__ pv_all,
    const float* __restrict__ pmu_all,
    const float* __restrict__ ws, float* __restrict__ out)
{
    const int tid = threadIdx.x;
    if (blockIdx.x == 0) {
        __shared__ float wred[4];
        __shared__ float skl[B_], sks[B_];
        const int start = B_ * pidx[0];
        float v = ws[WS_LLP + tid] + ws[WS_LLP + 256 + tid];
        #pragma unroll
        for (int ofs = 1; ofs < 64; ofs <<= 1) v += __shfl_xor(v, ofs, 64);
        if ((tid & 63) == 0) wred[tid >> 6] = v;

        if (tid < B_) {
            int r = start + tid;
            float kl = 0.f;
            for (int l = 0; l < L_; ++l) {
                float qmv = qm_all[(size_t)r * L_ + l];
                float qlv = qlv_all[(size_t)r * L_ + l];
                float mp  = pm_all[(size_t)r * L_ + l];
                float vp  = pv_all[(size_t)r * L_ + l];
                float d   = qmv - mp;
                kl += __logf(vp) - qlv + (__expf(qlv) + d * d) / vp - 1.f;
            }
            skl[tid] = 0.5f * kl;

            float qsum = 0.f, psum = 0.f;
            #pragma unroll
            for (int j = 0; j < K_; ++j) {
                qsum += qs_all[(size_t)r * K_ + j];
                psum += pmu_all[(size_t)r * K_ + j];
            }
            float ks = 0.f;
            #pragma unroll
            for (int j = 0; j < K_; ++j) {
                float qn = qs_all[(size_t)r * K_ + j] / qsum;
                float pn = pmu_all[(size_t)r * K_ + j] / psum;
                ks += qn * (__logf(qn) - __logf(pn));
            }
            sks[tid] = ks;
        }
        __syncthreads();
        if (tid == 0) {
            float LL = wred[0] + wred[1] + wred[2] + wred[3];
            float sklz = 0.f, skls = 0.f;
            for (int i = 0; i < B_; ++i) { sklz += skl[i]; skls += sks[i]; }
            float elbo = LL - sklz - skls;
            out[0] = -elbo;
            out[1] = LL;
            out[2] = skl[B_ - 1];
            out[3] = sks[B_ - 1];
        }
    } else if (blockIdx.x <= 12) {
        int g = (blockIdx.x - 1) * 256 + tid;
        if (g < 3 * M_) {
            int i = g / M_, m = g % M_;
            int rt = m >> 4, cx = m & 15;
            float s = 0.f;
            #pragma unroll 8
            for (int b2 = 0; b2 < 32; ++b2)
                s += ws[WS_PART + ((size_t)b2 * 64 + rt) * 48 + i * 16 + cx];
            if (i == 0) s = -0.5f * (32.f * ws[WS_C1 + 8] + s);
            out[OUT_T1 + i * M_ + m] = s;
        }
    } else {
        int i = (blockIdx.x - 13) * 256 + tid;   // [0, N*K)
        int r = i >> 3, c = i & 7;
        int start = B_ * pidx[0];
        float v = 0.f;
        if (r >= start && r < start + B_) {
            const float* row = qs_all + (size_t)r * K_;
            float mx = row[0];
            #pragma unroll
            for (int jj = 1; jj < K_; ++jj) mx = fmaxf(mx, row[jj]);
            float se = 0.f;
            #pragma unroll
            for (int jj = 0; jj < K_; ++jj) se += __expf(row[jj] - mx);
            v = __expf(row[c] - mx) / se;
        }
        out[OUT_RIK + i] = v;
    }
}

extern "C" void kernel_launch(void* const* d_in, const int* in_sizes, int n_in,
                              void* d_out, int out_size, void* d_ws, size_t ws_size,
                              hipStream_t stream)
{
    (void)in_sizes; (void)n_in; (void)out_size; (void)ws_size;
    const int*   pidx = (const int*)d_in[0];
    const float* Xc   = (const float*)d_in[1];
    const float* Xb   = (const float*)d_in[2];
    const int*   Xd   = (const int*)d_in[3];
    const float* qm   = (const float*)d_in[4];
    const float* qlv  = (const float*)d_in[5];
    const float* qs   = (const float*)d_in[6];
    const float* pm   = (const float*)d_in[7];
    const float* pv   = (const float*)d_in[8];
    const float* pmu  = (const float*)d_in[9];
    const float* Wg   = (const float*)d_in[10];
    const float* bg   = (const float*)d_in[11];
    const float* lvg  = (const float*)d_in[12];
    const float* Wb   = (const float*)d_in[13];
    const float* bb   = (const float*)d_in[14];
    const float* Wd   = (const float*)d_in[15];
    const float* bd   = (const float*)d_in[16];
    const float* eps  = (const float*)d_in[17];
    float* out = (float*)d_out;
    float* ws  = (float*)d_ws;

    mm_prep<<<(PC1 + 255) / 256, 256, 0, stream>>>(Wg, bg, lvg, Wb, bb, Wd, bd, ws);

    dim3 grid(16, 32);   // (64-row m-group, b)
    mm_main<<<grid, 512, 0, stream>>>(pidx, Xc, Xb, Xd, qm, qlv, qs, eps, ws);

    mm_final<<<141, 256, 0, stream>>>(pidx, qm, qlv, qs, pm, pv, pmu, ws, out);
}